// Round 1
// baseline (3843.740 us; speedup 1.0000x reference)
//
#include <hip/hip_runtime.h>
#include <math.h>

#define BS 4
#define CC 28          // total channels in obs / maps
#define NF 25          // 1 + NUM_SEM splat feature channels
#define HS 240
#define WSC 320
#define NPIX (HS*WSC)
#define VR 100
#define ZD 80
#define MC 480
#define VOX_PER_F (VR*VR*ZD)            // 800000 floats per (b,f) plane
#define GRID_FLOATS_B ((size_t)NF*VOX_PER_F)  // 20,000,000 floats per batch

__device__ __forceinline__ float clip01(float v){ return fminf(fmaxf(v, 0.f), 1.f); }

// ---------------- pose + sampling params ----------------
__global__ void pose_kernel(const float* __restrict__ pose_obs,
                            const float* __restrict__ poses_last,
                            float* __restrict__ out_p1,
                            float* __restrict__ out_p2,
                            float* __restrict__ params){
    int b = threadIdx.x;
    if (b >= BS) return;
    const float R2D = 57.29577951308232f;
    float th0 = poses_last[b*3+2] / R2D;
    float s0 = sinf(th0), c0 = cosf(th0);
    float ny = poses_last[b*3+1] + pose_obs[b*3+0]*s0 + pose_obs[b*3+1]*c0;
    float nx = poses_last[b*3+0] + pose_obs[b*3+0]*c0 - pose_obs[b*3+1]*s0;
    float no = poses_last[b*3+2] + pose_obs[b*3+2]*R2D;
    no = fmodf(no - 180.f, 360.f) + 180.f;
    no = fmodf(no + 180.f, 360.f) - 180.f;
    out_p1[b*3+0] = nx; out_p1[b*3+1] = ny; out_p1[b*3+2] = no;
    out_p2[b*3+0] = nx; out_p2[b*3+1] = ny; out_p2[b*3+2] = no;
    const float half = 240.f;
    float sx = -(nx*100.f/5.f - half)/half;
    float sy = -(ny*100.f/5.f - half)/half;
    float t = (90.f - no) * 0.017453292519943295f;
    params[b*4+0] = cosf(t);
    params[b*4+1] = sinf(t);
    params[b*4+2] = sx;
    params[b*4+3] = sy;
}

// ---------------- trilinear splat into voxel grid ----------------
__global__ void splat_kernel(const float* __restrict__ obs,
                             const float* __restrict__ view_angles,
                             float* __restrict__ grid,
                             int b_base, int nb){
    long tid = (long)blockIdx.x * blockDim.x + threadIdx.x;
    long total = (long)nb * NF * NPIX;
    if (tid >= total) return;
    int pix = (int)(tid % NPIX);
    int rest = (int)(tid / NPIX);
    int f  = rest % NF;
    int bl = rest / NF;
    int b  = b_base + bl;
    int j = pix % WSC;
    int i = pix / WSC;

    float depth = obs[((long)(b*CC + 3))*NPIX + pix];
    if (depth < 0.f) depth = 10000.f;
    const float FOCAL = 277.12812921102035f;
    float X = ((float)j - 159.5f) * depth / FOCAL;
    float Z = ((float)(HS-1-i) - 119.5f) * depth / FOCAL;
    float a = view_angles[b] * 0.017453292519943295f;
    float ca = cosf(a), sa = sinf(a);
    float Y2 = ca*depth - sa*Z;
    float Z2 = sa*depth + ca*Z + 155.f;   // + AGENT_HEIGHT
    float X2 = X + 250.f;                 // + SHIFT_X

    // replicate reference arithmetic chain exactly
    float px = ((X2/5.f - 50.f)/100.f*2.f)*50.f + 50.f;
    float py = ((Y2/5.f - 50.f)/100.f*2.f)*50.f + 50.f;
    float pz = ((Z2/5.f - 32.f)/80.f*2.f)*40.f + 40.f;

    float fx = floorf(px), fy = floorf(py), fz = floorf(pz);
    float wx[2], wy[2], wz[2];
    int   xi[2], yi[2], zi[2];
    {
        float p0 = fx, p1 = fx + 1.f;
        bool s0 = (p0 > 0.f) && (p0 < 100.f);
        bool s1 = (p1 > 0.f) && (p1 < 100.f);
        wx[0] = s0 ? (1.f - fabsf(px - p0)) : 0.f;
        wx[1] = s1 ? (1.f - fabsf(px - p1)) : 0.f;
        xi[0] = s0 ? (int)p0 : 0;
        xi[1] = s1 ? (int)p1 : 0;
    }
    {
        float p0 = fy, p1 = fy + 1.f;
        bool s0 = (p0 > 0.f) && (p0 < 100.f);
        bool s1 = (p1 > 0.f) && (p1 < 100.f);
        wy[0] = s0 ? (1.f - fabsf(py - p0)) : 0.f;
        wy[1] = s1 ? (1.f - fabsf(py - p1)) : 0.f;
        yi[0] = s0 ? (int)p0 : 0;
        yi[1] = s1 ? (int)p1 : 0;
    }
    {
        float p0 = fz, p1 = fz + 1.f;
        bool s0 = (p0 > 0.f) && (p0 < 80.f);
        bool s1 = (p1 > 0.f) && (p1 < 80.f);
        wz[0] = s0 ? (1.f - fabsf(pz - p0)) : 0.f;
        wz[1] = s1 ? (1.f - fabsf(pz - p1)) : 0.f;
        zi[0] = s0 ? (int)p0 : 0;
        zi[1] = s1 ? (int)p1 : 0;
    }

    float val = (f == 0) ? 1.f : obs[((long)(b*CC + 3 + f))*NPIX + pix];
    float* g = grid + (long)(bl*NF + f) * VOX_PER_F;

    #pragma unroll
    for (int cx = 0; cx < 2; ++cx){
        #pragma unroll
        for (int cy = 0; cy < 2; ++cy){
            float wxy = wx[cx] * wy[cy];     // matches ref product order (wx*wy)*wz
            int baseI = (yi[cy]*VR + xi[cx]) * ZD;   // layout [f][y][x][z]
            #pragma unroll
            for (int cz = 0; cz < 2; ++cz){
                float w = wxy * wz[cz];
                if (w != 0.f)
                    atomicAdd(&g[baseI + zi[cz]], val * w);
            }
        }
    }
}

// ---------------- per-column round + z-projection ----------------
__global__ void project_kernel(const float* __restrict__ grid,
                               float* __restrict__ ahp,
                               float* __restrict__ allp,
                               int b_base, int nb){
    int tid = blockIdx.x * blockDim.x + threadIdx.x;
    int total = nb * NF * VR * VR;
    if (tid >= total) return;
    int x  = tid % VR;
    int y  = (tid / VR) % VR;
    int f  = (tid / (VR*VR)) % NF;
    int bl = tid / (VR*VR*NF);
    int b  = b_base + bl;

    const float4* col = (const float4*)(grid + (long)(bl*NF + f)*VOX_PER_F
                                             + (long)(y*VR + x)*ZD);
    float s_all = 0.f, s_ag = 0.f;
    #pragma unroll
    for (int k = 0; k < 20; ++k){
        float4 q = col[k];
        float v0 = rintf(q.x), v1 = rintf(q.y), v2 = rintf(q.z), v3 = rintf(q.w);
        s_all += v0 + v1 + v2 + v3;      // integer-valued: exact
        int z = 4*k;
        if (z+0 >= 11 && z+0 < 49) s_ag += v0;
        if (z+1 >= 11 && z+1 < 49) s_ag += v1;
        if (z+2 >= 11 && z+2 < 49) s_ag += v2;
        if (z+3 >= 11 && z+3 < 49) s_ag += v3;
    }
    ahp[((long)(b*NF + f)*VR + y)*VR + x] = s_ag;
    if (f == 0) allp[((long)b*VR + y)*VR + x] = s_all;
}

// ---------------- output 0 ----------------
__global__ void fpmap_kernel(const float* __restrict__ ahp, float* __restrict__ out0){
    int tid = blockIdx.x * blockDim.x + threadIdx.x;
    if (tid >= BS*VR*VR) return;
    int b  = tid / (VR*VR);
    int yx = tid % (VR*VR);
    out0[tid] = clip01(ahp[(long)b*NF*VR*VR + yx]);
}

// ---------------- fused rotate+translate grid_sample + max ----------------
__global__ void final_kernel(const float* __restrict__ ahp,
                             const float* __restrict__ allp,
                             const float* __restrict__ params,
                             const float* __restrict__ maps_last,
                             float* __restrict__ out1){
    int tid = blockIdx.x * blockDim.x + threadIdx.x;
    if (tid >= BS*MC*MC) return;
    int w = tid % MC;
    int h = (tid / MC) % MC;
    int b = tid / (MC*MC);

    float ct = params[b*4+0], st = params[b*4+1];
    float sx = params[b*4+2], sy = params[b*4+3];

    float gx = -1.f + 2.f*(float)w/479.f;
    float gy = -1.f + 2.f*(float)h/479.f;
    float ix = (gx + sx + 1.f)*0.5f*479.f;
    float iy = (gy + sy + 1.f)*0.5f*479.f;
    float x0 = floorf(ix), y0 = floorf(iy);
    float wx1 = ix - x0, wx0 = 1.f - wx1;
    float wy1 = iy - y0, wy0 = 1.f - wy1;

    int   offs[16];
    float wt16[16];
    int nz = 0;
    #pragma unroll
    for (int tc = 0; tc < 4; ++tc){
        float txf = (tc & 1) ? x0 + 1.f : x0;
        float tyf = (tc & 2) ? y0 + 1.f : y0;
        float wt  = ((tc & 1) ? wx1 : wx0) * ((tc & 2) ? wy1 : wy0);
        bool validT = (txf >= 0.f) && (txf <= 479.f) && (tyf >= 0.f) && (tyf <= 479.f);
        int txc = (int)fminf(fmaxf(txf, 0.f), 479.f);
        int tyc = (int)fminf(fmaxf(tyf, 0.f), 479.f);

        // rotate-stage sample at integer pixel (tyc, txc)
        float gx2 = -1.f + 2.f*(float)txc/479.f;
        float gy2 = -1.f + 2.f*(float)tyc/479.f;
        float rgx = ct*gx2 - st*gy2;
        float rgy = st*gx2 + ct*gy2;
        float ixr = (rgx + 1.f)*0.5f*479.f;
        float iyr = (rgy + 1.f)*0.5f*479.f;
        float rx0 = floorf(ixr), ry0 = floorf(iyr);
        float rwx1 = ixr - rx0, rwx0 = 1.f - rwx1;
        float rwy1 = iyr - ry0, rwy0 = 1.f - rwy1;

        #pragma unroll
        for (int rc = 0; rc < 4; ++rc){
            int id = tc*4 + rc;
            float rxf = (rc & 1) ? rx0 + 1.f : rx0;
            float ryf = (rc & 2) ? ry0 + 1.f : ry0;
            float wr  = ((rc & 1) ? rwx1 : rwx0) * ((rc & 2) ? rwy1 : rwy0);
            bool validR = (rxf >= 0.f) && (rxf <= 479.f) && (ryf >= 0.f) && (ryf <= 479.f);
            int rxc = (int)fminf(fmaxf(rxf, 0.f), 479.f);
            int ryc = (int)fminf(fmaxf(ryf, 0.f), 479.f);
            // agent_view nonzero window: x in [190,290), y in [240,336)
            bool inwin = validT && validR &&
                         (rxc >= 190) && (rxc < 290) && (ryc >= 240) && (ryc < 336);
            float wgt = wt * wr;
            if (inwin && wgt != 0.f){
                offs[id] = (ryc - 240)*VR + (rxc - 190);
                wt16[id] = wgt;
                nz++;
            } else {
                offs[id] = -1;
                wt16[id] = 0.f;
            }
        }
    }

    long outBase = (long)b*CC*MC*MC + (long)h*MC + w;
    if (nz == 0){
        #pragma unroll
        for (int ch = 0; ch < CC; ++ch){
            long o = outBase + (long)ch*MC*MC;
            out1[o] = fmaxf(maps_last[o], 0.f);
        }
        return;
    }

    const float* ahp_b  = ahp  + (long)b*NF*VR*VR;
    const float* allp_b = allp + (long)b*VR*VR;
    for (int ch = 0; ch < CC; ++ch){
        float acc = 0.f;
        if (ch != 2 && ch != 3){
            #pragma unroll
            for (int id = 0; id < 16; ++id){
                if (offs[id] >= 0){
                    float v;
                    if (ch == 0)      v = clip01(ahp_b[offs[id]]);
                    else if (ch == 1) v = clip01(allp_b[offs[id]]);
                    else              v = clip01(ahp_b[(long)(ch-3)*VR*VR + offs[id]] / 5.f);
                    acc += wt16[id] * v;
                }
            }
        }
        long o = outBase + (long)ch*MC*MC;
        out1[o] = fmaxf(maps_last[o], acc);
    }
}

extern "C" void kernel_launch(void* const* d_in, const int* in_sizes, int n_in,
                              void* d_out, int out_size, void* d_ws, size_t ws_size,
                              hipStream_t stream){
    const float* obs         = (const float*)d_in[0];
    const float* pose_obs    = (const float*)d_in[1];
    const float* maps_last   = (const float*)d_in[2];
    const float* poses_last  = (const float*)d_in[3];
    const float* view_angles = (const float*)d_in[4];
    float* out = (float*)d_out;

    const long OUT0 = (long)BS*VR*VR;        // 40000
    const long OUT1 = (long)BS*CC*MC*MC;     // 25804800
    float* out0 = out;
    float* out1 = out + OUT0;
    float* out2 = out + OUT0 + OUT1;
    float* out3 = out2 + BS*3;

    const size_t GRID_BYTES_B = GRID_FLOATS_B * 4;     // 80 MB per batch
    const size_t SMALL_FLOATS = (size_t)BS*NF*VR*VR + (size_t)BS*VR*VR + BS*4;
    const size_t SMALL_BYTES  = SMALL_FLOATS * 4;      // ~4.16 MB

    float* grid;
    float* small;
    int nbg;   // batches resident in grid scratch at once
    if (ws_size >= 4*GRID_BYTES_B + SMALL_BYTES){
        grid  = (float*)d_ws;
        small = grid + 4*GRID_FLOATS_B;
        nbg = 4;
    } else if (ws_size >= GRID_BYTES_B + SMALL_BYTES){
        grid  = (float*)d_ws;
        small = grid + GRID_FLOATS_B;
        nbg = 1;
    } else {
        // alias the per-batch grid into the (not-yet-written) map_pred output region
        grid  = out1;              // 25.8M floats >= 20M needed
        small = (float*)d_ws;      // needs ~4.16 MB
        nbg = 1;
    }
    float* ahp    = small;
    float* allp   = ahp  + (size_t)BS*NF*VR*VR;
    float* params = allp + (size_t)BS*VR*VR;

    pose_kernel<<<1, 64, 0, stream>>>(pose_obs, poses_last, out2, out3, params);

    if (nbg == 4){
        hipMemsetAsync(grid, 0, 4*GRID_BYTES_B, stream);
        long tot = (long)4*NF*NPIX;
        splat_kernel<<<(int)((tot + 255)/256), 256, 0, stream>>>(obs, view_angles, grid, 0, 4);
        int tot2 = 4*NF*VR*VR;
        project_kernel<<<(tot2 + 255)/256, 256, 0, stream>>>(grid, ahp, allp, 0, 4);
    } else {
        for (int b = 0; b < BS; ++b){
            hipMemsetAsync(grid, 0, GRID_BYTES_B, stream);
            long tot = (long)NF*NPIX;
            splat_kernel<<<(int)((tot + 255)/256), 256, 0, stream>>>(obs, view_angles, grid, b, 1);
            int tot2 = NF*VR*VR;
            project_kernel<<<(tot2 + 255)/256, 256, 0, stream>>>(grid, ahp, allp, b, 1);
        }
    }

    fpmap_kernel<<<(BS*VR*VR + 255)/256, 256, 0, stream>>>(ahp, out0);
    int tot3 = BS*MC*MC;
    final_kernel<<<(tot3 + 255)/256, 256, 0, stream>>>(ahp, allp, params, maps_last, out1);
}

// Round 2
// 3588.853 us; speedup vs baseline: 1.0710x; 1.0710x over previous
//
#include <hip/hip_runtime.h>
#include <math.h>

#define BS 4
#define CC 28          // total channels in obs / maps
#define NF 25          // 1 + NUM_SEM splat feature channels
#define HS 240
#define WSC 320
#define NPIX (HS*WSC)
#define VR 100
#define ZD 80
#define MC 480
#define GRID_FLOATS_B ((size_t)VR*VR*ZD*NF)   // 20,000,000 floats per batch (80 MB)

__device__ __forceinline__ float clip01(float v){ return fminf(fmaxf(v, 0.f), 1.f); }

// ---------------- pose + sampling params ----------------
__global__ void pose_kernel(const float* __restrict__ pose_obs,
                            const float* __restrict__ poses_last,
                            float* __restrict__ out_p1,
                            float* __restrict__ out_p2,
                            float* __restrict__ params){
    int b = threadIdx.x;
    if (b >= BS) return;
    const float R2D = 57.29577951308232f;
    float th0 = poses_last[b*3+2] / R2D;
    float s0 = sinf(th0), c0 = cosf(th0);
    float ny = poses_last[b*3+1] + pose_obs[b*3+0]*s0 + pose_obs[b*3+1]*c0;
    float nx = poses_last[b*3+0] + pose_obs[b*3+0]*c0 - pose_obs[b*3+1]*s0;
    float no = poses_last[b*3+2] + pose_obs[b*3+2]*R2D;
    no = fmodf(no - 180.f, 360.f) + 180.f;
    no = fmodf(no + 180.f, 360.f) - 180.f;
    out_p1[b*3+0] = nx; out_p1[b*3+1] = ny; out_p1[b*3+2] = no;
    out_p2[b*3+0] = nx; out_p2[b*3+1] = ny; out_p2[b*3+2] = no;
    const float half = 240.f;
    float sx = -(nx*100.f/5.f - half)/half;
    float sy = -(ny*100.f/5.f - half)/half;
    float t = (90.f - no) * 0.017453292519943295f;
    params[b*4+0] = cosf(t);
    params[b*4+1] = sinf(t);
    params[b*4+2] = sx;
    params[b*4+3] = sy;
}

// ---------------- trilinear splat: one thread per pixel, f innermost ----------------
// grid layout: [bl][y][x][z][f]  (f contiguous, 25 floats = 100 B per voxel)
__global__ void splat_kernel(const float* __restrict__ obs,
                             const float* __restrict__ view_angles,
                             float* __restrict__ grid,
                             int b_base, int nb){
    int tid = blockIdx.x * blockDim.x + threadIdx.x;
    if (tid >= nb * NPIX) return;
    int pix = tid % NPIX;
    int bl  = tid / NPIX;
    int b   = b_base + bl;
    int j = pix % WSC;
    int i = pix / WSC;

    float depth = obs[((size_t)(b*CC + 3))*NPIX + pix];
    if (depth < 0.f) depth = 10000.f;
    const float FOCAL = 277.12812921102035f;
    float X = ((float)j - 159.5f) * depth / FOCAL;
    float Z = ((float)(HS-1-i) - 119.5f) * depth / FOCAL;
    float a = view_angles[b] * 0.017453292519943295f;
    float ca = cosf(a), sa = sinf(a);
    float Y2 = ca*depth - sa*Z;
    float Z2 = sa*depth + ca*Z + 155.f;   // + AGENT_HEIGHT
    float X2 = X + 250.f;                 // + SHIFT_X

    // replicate reference arithmetic chain exactly
    float px = ((X2/5.f - 50.f)/100.f*2.f)*50.f + 50.f;
    float py = ((Y2/5.f - 50.f)/100.f*2.f)*50.f + 50.f;
    float pz = ((Z2/5.f - 32.f)/80.f*2.f)*40.f + 40.f;

    float fx = floorf(px), fy = floorf(py), fz = floorf(pz);
    float wx[2], wy[2], wz[2];
    int   xi[2], yi[2], zi[2];
    {
        float p0 = fx, p1 = fx + 1.f;
        bool s0 = (p0 > 0.f) && (p0 < 100.f);
        bool s1 = (p1 > 0.f) && (p1 < 100.f);
        wx[0] = s0 ? (1.f - fabsf(px - p0)) : 0.f;
        wx[1] = s1 ? (1.f - fabsf(px - p1)) : 0.f;
        xi[0] = s0 ? (int)p0 : 0;
        xi[1] = s1 ? (int)p1 : 0;
    }
    {
        float p0 = fy, p1 = fy + 1.f;
        bool s0 = (p0 > 0.f) && (p0 < 100.f);
        bool s1 = (p1 > 0.f) && (p1 < 100.f);
        wy[0] = s0 ? (1.f - fabsf(py - p0)) : 0.f;
        wy[1] = s1 ? (1.f - fabsf(py - p1)) : 0.f;
        yi[0] = s0 ? (int)p0 : 0;
        yi[1] = s1 ? (int)p1 : 0;
    }
    {
        float p0 = fz, p1 = fz + 1.f;
        bool s0 = (p0 > 0.f) && (p0 < 80.f);
        bool s1 = (p1 > 0.f) && (p1 < 80.f);
        wz[0] = s0 ? (1.f - fabsf(pz - p0)) : 0.f;
        wz[1] = s1 ? (1.f - fabsf(pz - p1)) : 0.f;
        zi[0] = s0 ? (int)p0 : 0;
        zi[1] = s1 ? (int)p1 : 0;
    }

    // 8 corner base addresses (in floats, f=0) and weights
    int   addr[8];
    float w8[8];
    #pragma unroll
    for (int cx = 0; cx < 2; ++cx)
    #pragma unroll
    for (int cy = 0; cy < 2; ++cy){
        float wxy = wx[cx] * wy[cy];            // matches ref product order (wx*wy)*wz
        int vox_xy = (yi[cy]*VR + xi[cx]) * ZD;
        #pragma unroll
        for (int cz = 0; cz < 2; ++cz){
            int id = (cx*2 + cy)*2 + cz;
            addr[id] = (vox_xy + zi[cz]) * NF;
            w8[id]   = wxy * wz[cz];
        }
    }

    float* gb = grid + (size_t)bl * GRID_FLOATS_B;
    const float* obs_b = obs + (size_t)(b*CC + 3) * NPIX + pix;  // channel 3+f at stride NPIX

    for (int f = 0; f < NF; ++f){
        float val = (f == 0) ? 1.f : obs_b[(size_t)f * NPIX];
        #pragma unroll
        for (int c = 0; c < 8; ++c){
            if (w8[c] != 0.f)
                atomicAdd(gb + addr[c] + f, val * w8[c]);
        }
    }
}

// ---------------- per-column round + z-projection (f-innermost layout) ----------------
// One thread per (b, y, x, z-quarter). Streams the column as float4 with a
// fully-unrolled period-100 element pattern so f = e%25 is compile-time.
#define PROJ_EL(comp, EE)                                        \
    {   const int e_ = (EE); const int f_ = e_%25, q_ = e_/25;   \
        float r_ = rintf(comp);                                  \
        if (f_ == 0) s_all += r_;                                \
        accf[f_] += m[q_] ? r_ : 0.f; }

__global__ void project_kernel(const float* __restrict__ grid,
                               float* __restrict__ ahp,
                               float* __restrict__ allp,
                               int b_base, int nb){
    int tid = blockIdx.x * blockDim.x + threadIdx.x;
    if (tid >= nb * VR * VR * 4) return;
    int x  = tid % VR;
    int y  = (tid / VR) % VR;
    int zq = (tid / (VR*VR)) % 4;
    int bl = tid / (VR*VR*4);
    int b  = b_base + bl;

    const float4* col = (const float4*)(grid + (size_t)bl * GRID_FLOATS_B
                                             + (size_t)(y*VR + x) * (ZD*NF));
    float accf[25];
    #pragma unroll
    for (int f = 0; f < 25; ++f) accf[f] = 0.f;
    float s_all = 0.f;

    for (int o = zq*5; o < zq*5 + 5; ++o){   // each o covers 4 z-levels (100 floats)
        int zb = 4*o;
        bool m[4];
        m[0] = (zb+0 >= 11) && (zb+0 < 49);
        m[1] = (zb+1 >= 11) && (zb+1 < 49);
        m[2] = (zb+2 >= 11) && (zb+2 < 49);
        m[3] = (zb+3 >= 11) && (zb+3 < 49);
        const float4* p = col + o*25;
        #pragma unroll
        for (int jj = 0; jj < 25; ++jj){
            float4 v = p[jj];
            PROJ_EL(v.x, 4*jj+0)
            PROJ_EL(v.y, 4*jj+1)
            PROJ_EL(v.z, 4*jj+2)
            PROJ_EL(v.w, 4*jj+3)
        }
    }

    int yx = y*VR + x;
    #pragma unroll
    for (int f = 0; f < 25; ++f)
        atomicAdd(ahp + (size_t)(b*NF + f)*VR*VR + yx, accf[f]);
    atomicAdd(allp + (size_t)b*VR*VR + yx, s_all);
}

// ---------------- output 0 ----------------
__global__ void fpmap_kernel(const float* __restrict__ ahp, float* __restrict__ out0){
    int tid = blockIdx.x * blockDim.x + threadIdx.x;
    if (tid >= BS*VR*VR) return;
    int b  = tid / (VR*VR);
    int yx = tid % (VR*VR);
    out0[tid] = clip01(ahp[(size_t)b*NF*VR*VR + yx]);
}

// ---------------- fused rotate+translate grid_sample + max ----------------
__global__ void final_kernel(const float* __restrict__ ahp,
                             const float* __restrict__ allp,
                             const float* __restrict__ params,
                             const float* __restrict__ maps_last,
                             float* __restrict__ out1){
    int tid = blockIdx.x * blockDim.x + threadIdx.x;
    if (tid >= BS*MC*MC) return;
    int w = tid % MC;
    int h = (tid / MC) % MC;
    int b = tid / (MC*MC);

    float ct = params[b*4+0], st = params[b*4+1];
    float sx = params[b*4+2], sy = params[b*4+3];

    float gx = -1.f + 2.f*(float)w/479.f;
    float gy = -1.f + 2.f*(float)h/479.f;
    float ix = (gx + sx + 1.f)*0.5f*479.f;
    float iy = (gy + sy + 1.f)*0.5f*479.f;
    float x0 = floorf(ix), y0 = floorf(iy);
    float wx1 = ix - x0, wx0 = 1.f - wx1;
    float wy1 = iy - y0, wy0 = 1.f - wy1;

    int   offs[16];
    float wt16[16];
    int nz = 0;
    #pragma unroll
    for (int tc = 0; tc < 4; ++tc){
        float txf = (tc & 1) ? x0 + 1.f : x0;
        float tyf = (tc & 2) ? y0 + 1.f : y0;
        float wt  = ((tc & 1) ? wx1 : wx0) * ((tc & 2) ? wy1 : wy0);
        bool validT = (txf >= 0.f) && (txf <= 479.f) && (tyf >= 0.f) && (tyf <= 479.f);
        int txc = (int)fminf(fmaxf(txf, 0.f), 479.f);
        int tyc = (int)fminf(fmaxf(tyf, 0.f), 479.f);

        float gx2 = -1.f + 2.f*(float)txc/479.f;
        float gy2 = -1.f + 2.f*(float)tyc/479.f;
        float rgx = ct*gx2 - st*gy2;
        float rgy = st*gx2 + ct*gy2;
        float ixr = (rgx + 1.f)*0.5f*479.f;
        float iyr = (rgy + 1.f)*0.5f*479.f;
        float rx0 = floorf(ixr), ry0 = floorf(iyr);
        float rwx1 = ixr - rx0, rwx0 = 1.f - rwx1;
        float rwy1 = iyr - ry0, rwy0 = 1.f - rwy1;

        #pragma unroll
        for (int rc = 0; rc < 4; ++rc){
            int id = tc*4 + rc;
            float rxf = (rc & 1) ? rx0 + 1.f : rx0;
            float ryf = (rc & 2) ? ry0 + 1.f : ry0;
            float wr  = ((rc & 1) ? rwx1 : rwx0) * ((rc & 2) ? rwy1 : rwy0);
            bool validR = (rxf >= 0.f) && (rxf <= 479.f) && (ryf >= 0.f) && (ryf <= 479.f);
            int rxc = (int)fminf(fmaxf(rxf, 0.f), 479.f);
            int ryc = (int)fminf(fmaxf(ryf, 0.f), 479.f);
            bool inwin = validT && validR &&
                         (rxc >= 190) && (rxc < 290) && (ryc >= 240) && (ryc < 336);
            float wgt = wt * wr;
            if (inwin && wgt != 0.f){
                offs[id] = (ryc - 240)*VR + (rxc - 190);
                wt16[id] = wgt;
                nz++;
            } else {
                offs[id] = -1;
                wt16[id] = 0.f;
            }
        }
    }

    size_t outBase = (size_t)b*CC*MC*MC + (size_t)h*MC + w;
    if (nz == 0){
        #pragma unroll
        for (int ch = 0; ch < CC; ++ch){
            size_t o = outBase + (size_t)ch*MC*MC;
            out1[o] = fmaxf(maps_last[o], 0.f);
        }
        return;
    }

    const float* ahp_b  = ahp  + (size_t)b*NF*VR*VR;
    const float* allp_b = allp + (size_t)b*VR*VR;
    for (int ch = 0; ch < CC; ++ch){
        float acc = 0.f;
        if (ch != 2 && ch != 3){
            #pragma unroll
            for (int id = 0; id < 16; ++id){
                if (offs[id] >= 0){
                    float v;
                    if (ch == 0)      v = clip01(ahp_b[offs[id]]);
                    else if (ch == 1) v = clip01(allp_b[offs[id]]);
                    else              v = clip01(ahp_b[(size_t)(ch-3)*VR*VR + offs[id]] / 5.f);
                    acc += wt16[id] * v;
                }
            }
        }
        size_t o = outBase + (size_t)ch*MC*MC;
        out1[o] = fmaxf(maps_last[o], acc);
    }
}

extern "C" void kernel_launch(void* const* d_in, const int* in_sizes, int n_in,
                              void* d_out, int out_size, void* d_ws, size_t ws_size,
                              hipStream_t stream){
    const float* obs         = (const float*)d_in[0];
    const float* pose_obs    = (const float*)d_in[1];
    const float* maps_last   = (const float*)d_in[2];
    const float* poses_last  = (const float*)d_in[3];
    const float* view_angles = (const float*)d_in[4];
    float* out = (float*)d_out;

    const size_t OUT0 = (size_t)BS*VR*VR;        // 40000
    const size_t OUT1 = (size_t)BS*CC*MC*MC;     // 25804800
    float* out0 = out;
    float* out1 = out + OUT0;
    float* out2 = out + OUT0 + OUT1;
    float* out3 = out2 + BS*3;

    const size_t GRID_BYTES_B = GRID_FLOATS_B * 4;                 // 80 MB per batch
    const size_t AHP_FLOATS   = (size_t)BS*NF*VR*VR;               // 1,000,000
    const size_t ALLP_FLOATS  = (size_t)BS*VR*VR;                  // 40,000
    const size_t SMALL_FLOATS = AHP_FLOATS + ALLP_FLOATS + BS*4;
    const size_t SMALL_BYTES  = SMALL_FLOATS * 4;                  // ~4.16 MB

    float* grid;
    float* small;
    int nbg;   // batches resident in grid scratch at once
    if (ws_size >= 4*GRID_BYTES_B + SMALL_BYTES){
        grid  = (float*)d_ws;
        small = grid + 4*GRID_FLOATS_B;
        nbg = 4;
    } else if (ws_size >= GRID_BYTES_B + SMALL_BYTES){
        grid  = (float*)d_ws;
        small = grid + GRID_FLOATS_B;
        nbg = 1;
    } else {
        grid  = out1;              // alias per-batch grid into not-yet-written map_pred
        small = (float*)d_ws;
        nbg = 1;
    }
    float* ahp    = small;
    float* allp   = ahp  + AHP_FLOATS;
    float* params = allp + ALLP_FLOATS;

    // zero the projection accumulators (atomically accumulated by project_kernel)
    hipMemsetAsync(ahp, 0, (AHP_FLOATS + ALLP_FLOATS)*4, stream);
    pose_kernel<<<1, 64, 0, stream>>>(pose_obs, poses_last, out2, out3, params);

    if (nbg == 4){
        hipMemsetAsync(grid, 0, 4*GRID_BYTES_B, stream);
        int tot = 4*NPIX;
        splat_kernel<<<(tot + 255)/256, 256, 0, stream>>>(obs, view_angles, grid, 0, 4);
        int tot2 = 4*VR*VR*4;
        project_kernel<<<(tot2 + 255)/256, 256, 0, stream>>>(grid, ahp, allp, 0, 4);
    } else {
        for (int b = 0; b < BS; ++b){
            hipMemsetAsync(grid, 0, GRID_BYTES_B, stream);
            int tot = NPIX;
            splat_kernel<<<(tot + 255)/256, 256, 0, stream>>>(obs, view_angles, grid, b, 1);
            int tot2 = VR*VR*4;
            project_kernel<<<(tot2 + 255)/256, 256, 0, stream>>>(grid, ahp, allp, b, 1);
        }
    }

    fpmap_kernel<<<(BS*VR*VR + 255)/256, 256, 0, stream>>>(ahp, out0);
    int tot3 = BS*MC*MC;
    final_kernel<<<(tot3 + 255)/256, 256, 0, stream>>>(ahp, allp, params, maps_last, out1);
}

// Round 3
// 1165.542 us; speedup vs baseline: 3.2978x; 3.0791x over previous
//
#include <hip/hip_runtime.h>
#include <math.h>

#define BS 4
#define CC 28          // total channels in obs / maps
#define NF 25          // 1 + NUM_SEM splat feature channels
#define HS 240
#define WSC 320
#define NPIX (HS*WSC)
#define VR 100
#define ZD 80
#define MC 480
#define NCELL (VR*VR)          // 10000 xy cells per batch
#define MAXREC ((size_t)BS*NPIX*4)   // 1,228,800 worst-case records

__device__ __forceinline__ float clip01(float v){ return fminf(fmaxf(v, 0.f), 1.f); }

// ---------------- shared geometry (must be identical in count/scatter/accum) ----------------
struct Geo {
    float wx[2], wy[2], wz[2];
    int   xi[2], yi[2], zi[2];
    bool  sx[2], sy[2], sz[2];
};

__device__ __forceinline__ Geo compute_geo(const float* __restrict__ obs,
                                           const float* __restrict__ view_angles,
                                           int b, int pix){
    int j = pix % WSC;
    int i = pix / WSC;
    float depth = obs[((size_t)(b*CC + 3))*NPIX + pix];
    if (depth < 0.f) depth = 10000.f;
    const float FOCAL = 277.12812921102035f;
    float X = ((float)j - 159.5f) * depth / FOCAL;
    float Z = ((float)(HS-1-i) - 119.5f) * depth / FOCAL;
    float a = view_angles[b] * 0.017453292519943295f;
    float ca = cosf(a), sa = sinf(a);
    float Y2 = ca*depth - sa*Z;
    float Z2 = sa*depth + ca*Z + 155.f;   // + AGENT_HEIGHT
    float X2 = X + 250.f;                 // + SHIFT_X

    // replicate reference arithmetic chain exactly
    float px = ((X2/5.f - 50.f)/100.f*2.f)*50.f + 50.f;
    float py = ((Y2/5.f - 50.f)/100.f*2.f)*50.f + 50.f;
    float pz = ((Z2/5.f - 32.f)/80.f*2.f)*40.f + 40.f;

    Geo g;
    float fx = floorf(px), fy = floorf(py), fz = floorf(pz);
    {
        float p0 = fx, p1 = fx + 1.f;
        g.sx[0] = (p0 > 0.f) && (p0 < 100.f);
        g.sx[1] = (p1 > 0.f) && (p1 < 100.f);
        g.wx[0] = g.sx[0] ? (1.f - fabsf(px - p0)) : 0.f;
        g.wx[1] = g.sx[1] ? (1.f - fabsf(px - p1)) : 0.f;
        g.xi[0] = g.sx[0] ? (int)p0 : 0;
        g.xi[1] = g.sx[1] ? (int)p1 : 0;
    }
    {
        float p0 = fy, p1 = fy + 1.f;
        g.sy[0] = (p0 > 0.f) && (p0 < 100.f);
        g.sy[1] = (p1 > 0.f) && (p1 < 100.f);
        g.wy[0] = g.sy[0] ? (1.f - fabsf(py - p0)) : 0.f;
        g.wy[1] = g.sy[1] ? (1.f - fabsf(py - p1)) : 0.f;
        g.yi[0] = g.sy[0] ? (int)p0 : 0;
        g.yi[1] = g.sy[1] ? (int)p1 : 0;
    }
    {
        float p0 = fz, p1 = fz + 1.f;
        g.sz[0] = (p0 > 0.f) && (p0 < 80.f);
        g.sz[1] = (p1 > 0.f) && (p1 < 80.f);
        g.wz[0] = g.sz[0] ? (1.f - fabsf(pz - p0)) : 0.f;
        g.wz[1] = g.sz[1] ? (1.f - fabsf(pz - p1)) : 0.f;
        g.zi[0] = g.sz[0] ? (int)p0 : 0;
        g.zi[1] = g.sz[1] ? (int)p1 : 0;
    }
    return g;
}

// ---------------- pose + sampling params ----------------
__global__ void pose_kernel(const float* __restrict__ pose_obs,
                            const float* __restrict__ poses_last,
                            float* __restrict__ out_p1,
                            float* __restrict__ out_p2,
                            float* __restrict__ params){
    int b = threadIdx.x;
    if (b >= BS) return;
    const float R2D = 57.29577951308232f;
    float th0 = poses_last[b*3+2] / R2D;
    float s0 = sinf(th0), c0 = cosf(th0);
    float ny = poses_last[b*3+1] + pose_obs[b*3+0]*s0 + pose_obs[b*3+1]*c0;
    float nx = poses_last[b*3+0] + pose_obs[b*3+0]*c0 - pose_obs[b*3+1]*s0;
    float no = poses_last[b*3+2] + pose_obs[b*3+2]*R2D;
    no = fmodf(no - 180.f, 360.f) + 180.f;
    no = fmodf(no + 180.f, 360.f) - 180.f;
    out_p1[b*3+0] = nx; out_p1[b*3+1] = ny; out_p1[b*3+2] = no;
    out_p2[b*3+0] = nx; out_p2[b*3+1] = ny; out_p2[b*3+2] = no;
    const float half = 240.f;
    float sx = -(nx*100.f/5.f - half)/half;
    float sy = -(ny*100.f/5.f - half)/half;
    float t = (90.f - no) * 0.017453292519943295f;
    params[b*4+0] = cosf(t);
    params[b*4+1] = sinf(t);
    params[b*4+2] = sx;
    params[b*4+3] = sy;
}

// ---------------- pass A: count records per (b, xy-cell) ----------------
__global__ void count_kernel(const float* __restrict__ obs,
                             const float* __restrict__ view_angles,
                             int* __restrict__ counts){
    int tid = blockIdx.x * blockDim.x + threadIdx.x;
    if (tid >= BS*NPIX) return;
    int b   = tid / NPIX;
    int pix = tid % NPIX;
    Geo g = compute_geo(obs, view_angles, b, pix);
    #pragma unroll
    for (int cy = 0; cy < 2; ++cy)
    #pragma unroll
    for (int cx = 0; cx < 2; ++cx){
        if (g.sx[cx] && g.sy[cy] && (g.wx[cx]*g.wy[cy] != 0.f))
            atomicAdd(&counts[b*NCELL + g.yi[cy]*VR + g.xi[cx]], 1);
    }
}

// ---------------- pass B: exclusive scan over 40000 counts ----------------
__global__ void scan_kernel(const int* __restrict__ counts,
                            int* __restrict__ bases,
                            int* __restrict__ cursor){
    __shared__ int part[1024];
    int t = threadIdx.x;
    const int TOT = BS*NCELL;       // 40000
    const int CH  = 40;             // 1024*40 >= 40000
    int beg = t*CH;
    int s = 0;
    for (int i = 0; i < CH; ++i){
        int idx = beg + i;
        if (idx < TOT) s += counts[idx];
    }
    part[t] = s;
    __syncthreads();
    for (int off = 1; off < 1024; off <<= 1){
        int v = (t >= off) ? part[t-off] : 0;
        __syncthreads();
        part[t] += v;
        __syncthreads();
    }
    int run = (t == 0) ? 0 : part[t-1];
    for (int i = 0; i < CH; ++i){
        int idx = beg + i;
        if (idx < TOT){
            bases[idx]  = run;
            cursor[idx] = run;
            run += counts[idx];
        }
    }
}

// ---------------- pass C: scatter records into bins ----------------
__global__ void scatter_kernel(const float* __restrict__ obs,
                               const float* __restrict__ view_angles,
                               int* __restrict__ cursor,
                               unsigned* __restrict__ records){
    int tid = blockIdx.x * blockDim.x + threadIdx.x;
    if (tid >= BS*NPIX) return;
    int b   = tid / NPIX;
    int pix = tid % NPIX;
    Geo g = compute_geo(obs, view_angles, b, pix);
    #pragma unroll
    for (int cy = 0; cy < 2; ++cy)
    #pragma unroll
    for (int cx = 0; cx < 2; ++cx){
        if (g.sx[cx] && g.sy[cy] && (g.wx[cx]*g.wy[cy] != 0.f)){
            int cid = b*NCELL + g.yi[cy]*VR + g.xi[cx];
            int pos = atomicAdd(&cursor[cid], 1);
            records[pos] = ((unsigned)tid << 2) | ((unsigned)cy << 1) | (unsigned)cx;
        }
    }
}

// ---------------- pass D: per-cell LDS accumulation + z-projection ----------------
// one block per (b, xy-cell); whole 80z x 25f column lives in LDS
__global__ void accum_kernel(const float* __restrict__ obs,
                             const float* __restrict__ view_angles,
                             const int* __restrict__ bases,
                             const int* __restrict__ cursor,
                             const unsigned* __restrict__ records,
                             float* __restrict__ ahp,
                             float* __restrict__ allp,
                             float* __restrict__ out0){
    __shared__ float col[ZD*NF];        // 2000 floats
    __shared__ float pall[200], pag[200];

    int cid = blockIdx.x;
    int b   = cid / NCELL;
    int rest = cid % NCELL;
    int y = rest / VR;
    int x = rest % VR;
    int t = threadIdx.x;

    for (int i = t; i < ZD*NF; i += 256) col[i] = 0.f;
    __syncthreads();

    int start = bases[cid];
    int end   = cursor[cid];           // bases + count after scatter

    int r = t / NF;                    // record slot within chunk (0..9)
    int f = t % NF;
    bool act = t < 250;

    for (int cb = start; cb < end; cb += 10){
        int idx = cb + r;
        if (act && idx < end){
            unsigned rec = records[idx];
            int cx   = rec & 1;
            int cy   = (rec >> 1) & 1;
            int pixg = rec >> 2;
            int pix  = pixg - b*NPIX;
            Geo g = compute_geo(obs, view_angles, b, pix);
            float wxy = g.wx[cx] * g.wy[cy];
            float val = (f == 0) ? 1.f : obs[((size_t)(b*CC + 3 + f))*NPIX + pix];
            #pragma unroll
            for (int cz = 0; cz < 2; ++cz){
                if (g.sz[cz]){
                    float w = wxy * g.wz[cz];   // matches ref (wx*wy)*wz order
                    if (w != 0.f)
                        atomicAdd(&col[g.zi[cz]*NF + f], val * w);
                }
            }
        }
    }
    __syncthreads();

    // projection: 200 threads = 25 f x 8 z-groups of 10
    if (t < 200){
        int ff = t % NF;
        int gq = t / NF;
        float sall = 0.f, sag = 0.f;
        for (int z = gq*10; z < gq*10 + 10; ++z){
            float rv = rintf(col[z*NF + ff]);
            sall += rv;
            if (z >= 11 && z < 49) sag += rv;   // agent-height z range
        }
        pall[t] = sall;
        pag[t]  = sag;
    }
    __syncthreads();
    if (t < NF){
        float a = 0.f, s = 0.f;
        #pragma unroll
        for (int gq = 0; gq < 8; ++gq){
            s += pall[gq*NF + t];
            a += pag[gq*NF + t];
        }
        ahp[(((size_t)b*NF + t)*VR + y)*VR + x] = a;
        if (t == 0){
            allp[((size_t)b*VR + y)*VR + x] = s;
            out0[(size_t)b*NCELL + y*VR + x] = clip01(a);   // fp_map_pred
        }
    }
}

// ---------------- fused rotate+translate grid_sample + max ----------------
__global__ void final_kernel(const float* __restrict__ ahp,
                             const float* __restrict__ allp,
                             const float* __restrict__ params,
                             const float* __restrict__ maps_last,
                             float* __restrict__ out1){
    int tid = blockIdx.x * blockDim.x + threadIdx.x;
    if (tid >= BS*MC*MC) return;
    int w = tid % MC;
    int h = (tid / MC) % MC;
    int b = tid / (MC*MC);

    float ct = params[b*4+0], st = params[b*4+1];
    float sx = params[b*4+2], sy = params[b*4+3];

    float gx = -1.f + 2.f*(float)w/479.f;
    float gy = -1.f + 2.f*(float)h/479.f;
    float ix = (gx + sx + 1.f)*0.5f*479.f;
    float iy = (gy + sy + 1.f)*0.5f*479.f;
    float x0 = floorf(ix), y0 = floorf(iy);
    float wx1 = ix - x0, wx0 = 1.f - wx1;
    float wy1 = iy - y0, wy0 = 1.f - wy1;

    int   offs[16];
    float wt16[16];
    int nz = 0;
    #pragma unroll
    for (int tc = 0; tc < 4; ++tc){
        float txf = (tc & 1) ? x0 + 1.f : x0;
        float tyf = (tc & 2) ? y0 + 1.f : y0;
        float wt  = ((tc & 1) ? wx1 : wx0) * ((tc & 2) ? wy1 : wy0);
        bool validT = (txf >= 0.f) && (txf <= 479.f) && (tyf >= 0.f) && (tyf <= 479.f);
        int txc = (int)fminf(fmaxf(txf, 0.f), 479.f);
        int tyc = (int)fminf(fmaxf(tyf, 0.f), 479.f);

        float gx2 = -1.f + 2.f*(float)txc/479.f;
        float gy2 = -1.f + 2.f*(float)tyc/479.f;
        float rgx = ct*gx2 - st*gy2;
        float rgy = st*gx2 + ct*gy2;
        float ixr = (rgx + 1.f)*0.5f*479.f;
        float iyr = (rgy + 1.f)*0.5f*479.f;
        float rx0 = floorf(ixr), ry0 = floorf(iyr);
        float rwx1 = ixr - rx0, rwx0 = 1.f - rwx1;
        float rwy1 = iyr - ry0, rwy0 = 1.f - rwy1;

        #pragma unroll
        for (int rc = 0; rc < 4; ++rc){
            int id = tc*4 + rc;
            float rxf = (rc & 1) ? rx0 + 1.f : rx0;
            float ryf = (rc & 2) ? ry0 + 1.f : ry0;
            float wr  = ((rc & 1) ? rwx1 : rwx0) * ((rc & 2) ? rwy1 : rwy0);
            bool validR = (rxf >= 0.f) && (rxf <= 479.f) && (ryf >= 0.f) && (ryf <= 479.f);
            int rxc = (int)fminf(fmaxf(rxf, 0.f), 479.f);
            int ryc = (int)fminf(fmaxf(ryf, 0.f), 479.f);
            bool inwin = validT && validR &&
                         (rxc >= 190) && (rxc < 290) && (ryc >= 240) && (ryc < 336);
            float wgt = wt * wr;
            if (inwin && wgt != 0.f){
                offs[id] = (ryc - 240)*VR + (rxc - 190);
                wt16[id] = wgt;
                nz++;
            } else {
                offs[id] = -1;
                wt16[id] = 0.f;
            }
        }
    }

    size_t outBase = (size_t)b*CC*MC*MC + (size_t)h*MC + w;
    if (nz == 0){
        #pragma unroll
        for (int ch = 0; ch < CC; ++ch){
            size_t o = outBase + (size_t)ch*MC*MC;
            out1[o] = fmaxf(maps_last[o], 0.f);
        }
        return;
    }

    const float* ahp_b  = ahp  + (size_t)b*NF*VR*VR;
    const float* allp_b = allp + (size_t)b*VR*VR;
    for (int ch = 0; ch < CC; ++ch){
        float acc = 0.f;
        if (ch != 2 && ch != 3){
            #pragma unroll
            for (int id = 0; id < 16; ++id){
                if (offs[id] >= 0){
                    float v;
                    if (ch == 0)      v = clip01(ahp_b[offs[id]]);
                    else if (ch == 1) v = clip01(allp_b[offs[id]]);
                    else              v = clip01(ahp_b[(size_t)(ch-3)*VR*VR + offs[id]] / 5.f);
                    acc += wt16[id] * v;
                }
            }
        }
        size_t o = outBase + (size_t)ch*MC*MC;
        out1[o] = fmaxf(maps_last[o], acc);
    }
}

extern "C" void kernel_launch(void* const* d_in, const int* in_sizes, int n_in,
                              void* d_out, int out_size, void* d_ws, size_t ws_size,
                              hipStream_t stream){
    const float* obs         = (const float*)d_in[0];
    const float* pose_obs    = (const float*)d_in[1];
    const float* maps_last   = (const float*)d_in[2];
    const float* poses_last  = (const float*)d_in[3];
    const float* view_angles = (const float*)d_in[4];
    float* out = (float*)d_out;

    const size_t OUT0 = (size_t)BS*VR*VR;        // 40000
    const size_t OUT1 = (size_t)BS*CC*MC*MC;     // 25,804,800
    float* out0 = out;
    float* out1 = out + OUT0;
    float* out2 = out + OUT0 + OUT1;
    float* out3 = out2 + BS*3;

    const size_t AHP_FLOATS  = (size_t)BS*NF*VR*VR;   // 1,000,000
    const size_t ALLP_FLOATS = (size_t)BS*VR*VR;      // 40,000
    const size_t SMALL_FLOATS = AHP_FLOATS + ALLP_FLOATS + BS*4;   // ~4.16 MB
    const size_t NCID = (size_t)BS*NCELL;             // 40,000
    const size_t BIN_WORDS = 3*NCID + MAXREC;         // counts+bases+cursor+records ≈ 5.4 MB

    // small arrays (read by final_kernel) must live in ws
    float* ahp    = (float*)d_ws;
    float* allp   = ahp  + AHP_FLOATS;
    float* params = allp + ALLP_FLOATS;

    // binning arrays: in ws if it fits, else in the tail of the (not-yet-written) out1
    int* binmem;
    if (ws_size >= (SMALL_FLOATS + BIN_WORDS)*4)
        binmem = (int*)(params + BS*4);
    else
        binmem = (int*)(out1 + OUT1 - BIN_WORDS);   // consumed before final_kernel writes out1
    int*      counts  = binmem;
    int*      bases   = counts + NCID;
    int*      cursor  = bases  + NCID;
    unsigned* records = (unsigned*)(cursor + NCID);

    hipMemsetAsync(counts, 0, NCID*4, stream);
    pose_kernel<<<1, 64, 0, stream>>>(pose_obs, poses_last, out2, out3, params);

    int npx = BS*NPIX;
    count_kernel<<<(npx + 255)/256, 256, 0, stream>>>(obs, view_angles, counts);
    scan_kernel<<<1, 1024, 0, stream>>>(counts, bases, cursor);
    scatter_kernel<<<(npx + 255)/256, 256, 0, stream>>>(obs, view_angles, cursor, records);
    accum_kernel<<<(int)NCID, 256, 0, stream>>>(obs, view_angles, bases, cursor, records,
                                                ahp, allp, out0);
    final_kernel<<<(BS*MC*MC + 255)/256, 256, 0, stream>>>(ahp, allp, params, maps_last, out1);
}

// Round 4
// 930.114 us; speedup vs baseline: 4.1325x; 1.2531x over previous
//
#include <hip/hip_runtime.h>
#include <math.h>

#define BS 4
#define CC 28          // total channels in obs / maps
#define NF 25          // 1 + NUM_SEM splat feature channels
#define HS 240
#define WSC 320
#define NPIX (HS*WSC)
#define VR 100
#define ZD 80
#define MC 480
#define NCELL (VR*VR)                  // 10000 xy cells per batch
#define NREC_MAX ((size_t)BS*NPIX*4)   // 1,228,800 worst-case records

__device__ __forceinline__ float clip01(float v){ return fminf(fmaxf(v, 0.f), 1.f); }

// ---------------- shared geometry (identical in prep/scatter) ----------------
struct Geo {
    float wx[2], wy[2], wz[2];
    int   xi[2], yi[2], zi[2];
    bool  sx[2], sy[2];
};

__device__ __forceinline__ Geo compute_geo(const float* __restrict__ obs,
                                           const float* __restrict__ view_angles,
                                           int b, int pix){
    int j = pix % WSC;
    int i = pix / WSC;
    float depth = obs[((size_t)(b*CC + 3))*NPIX + pix];
    if (depth < 0.f) depth = 10000.f;
    const float FOCAL = 277.12812921102035f;
    float X = ((float)j - 159.5f) * depth / FOCAL;
    float Z = ((float)(HS-1-i) - 119.5f) * depth / FOCAL;
    float a = view_angles[b] * 0.017453292519943295f;
    float ca = cosf(a), sa = sinf(a);
    float Y2 = ca*depth - sa*Z;
    float Z2 = sa*depth + ca*Z + 155.f;   // + AGENT_HEIGHT
    float X2 = X + 250.f;                 // + SHIFT_X

    // replicate reference arithmetic chain exactly
    float px = ((X2/5.f - 50.f)/100.f*2.f)*50.f + 50.f;
    float py = ((Y2/5.f - 50.f)/100.f*2.f)*50.f + 50.f;
    float pz = ((Z2/5.f - 32.f)/80.f*2.f)*40.f + 40.f;

    Geo g;
    float fx = floorf(px), fy = floorf(py), fz = floorf(pz);
    {
        float p0 = fx, p1 = fx + 1.f;
        g.sx[0] = (p0 > 0.f) && (p0 < 100.f);
        g.sx[1] = (p1 > 0.f) && (p1 < 100.f);
        g.wx[0] = g.sx[0] ? (1.f - fabsf(px - p0)) : 0.f;
        g.wx[1] = g.sx[1] ? (1.f - fabsf(px - p1)) : 0.f;
        g.xi[0] = g.sx[0] ? (int)p0 : 0;
        g.xi[1] = g.sx[1] ? (int)p1 : 0;
    }
    {
        float p0 = fy, p1 = fy + 1.f;
        g.sy[0] = (p0 > 0.f) && (p0 < 100.f);
        g.sy[1] = (p1 > 0.f) && (p1 < 100.f);
        g.wy[0] = g.sy[0] ? (1.f - fabsf(py - p0)) : 0.f;
        g.wy[1] = g.sy[1] ? (1.f - fabsf(py - p1)) : 0.f;
        g.yi[0] = g.sy[0] ? (int)p0 : 0;
        g.yi[1] = g.sy[1] ? (int)p1 : 0;
    }
    {
        float p0 = fz, p1 = fz + 1.f;
        bool s0 = (p0 > 0.f) && (p0 < 80.f);
        bool s1 = (p1 > 0.f) && (p1 < 80.f);
        g.wz[0] = s0 ? (1.f - fabsf(pz - p0)) : 0.f;
        g.wz[1] = s1 ? (1.f - fabsf(pz - p1)) : 0.f;
        g.zi[0] = s0 ? (int)p0 : 0;
        g.zi[1] = s1 ? (int)p1 : 0;
    }
    return g;
}

// ---------------- pose + sampling params ----------------
__global__ void pose_kernel(const float* __restrict__ pose_obs,
                            const float* __restrict__ poses_last,
                            float* __restrict__ out_p1,
                            float* __restrict__ out_p2,
                            float* __restrict__ params){
    int b = threadIdx.x;
    if (b >= BS) return;
    const float R2D = 57.29577951308232f;
    float th0 = poses_last[b*3+2] / R2D;
    float s0 = sinf(th0), c0 = cosf(th0);
    float ny = poses_last[b*3+1] + pose_obs[b*3+0]*s0 + pose_obs[b*3+1]*c0;
    float nx = poses_last[b*3+0] + pose_obs[b*3+0]*c0 - pose_obs[b*3+1]*s0;
    float no = poses_last[b*3+2] + pose_obs[b*3+2]*R2D;
    no = fmodf(no - 180.f, 360.f) + 180.f;
    no = fmodf(no + 180.f, 360.f) - 180.f;
    out_p1[b*3+0] = nx; out_p1[b*3+1] = ny; out_p1[b*3+2] = no;
    out_p2[b*3+0] = nx; out_p2[b*3+1] = ny; out_p2[b*3+2] = no;
    const float half = 240.f;
    float sx = -(nx*100.f/5.f - half)/half;
    float sy = -(ny*100.f/5.f - half)/half;
    float t = (90.f - no) * 0.017453292519943295f;
    params[b*4+0] = cosf(t);
    params[b*4+1] = sinf(t);
    params[b*4+2] = sx;
    params[b*4+3] = sy;
}

// ---------------- pass A: count records + transpose features ----------------
// grid = BS*NPIX/256 blocks (NPIX % 256 == 0, so a block never straddles batches)
__global__ __launch_bounds__(256)
void prep_kernel(const float* __restrict__ obs,
                 const float* __restrict__ view_angles,
                 int* __restrict__ counts,
                 float* __restrict__ feat){
    __shared__ float sf[6400];          // 256 px * 24 f, padded stride 25
    int t   = threadIdx.x;
    int tid = blockIdx.x * 256 + t;
    int b   = tid / NPIX;
    int pix = tid % NPIX;

    Geo g = compute_geo(obs, view_angles, b, pix);
    #pragma unroll
    for (int cy = 0; cy < 2; ++cy)
    #pragma unroll
    for (int cx = 0; cx < 2; ++cx){
        if (g.sx[cx] && g.sy[cy] && (g.wx[cx]*g.wy[cy] != 0.f))
            atomicAdd(&counts[b*NCELL + g.yi[cy]*VR + g.xi[cx]], 1);
    }

    // stage this block's 256x24 feature slab in LDS (pad 25 -> conflict-free)
    #pragma unroll 6
    for (int f = 0; f < 24; ++f)
        sf[t*25 + f] = obs[((size_t)(b*CC + 4 + f))*NPIX + pix];
    __syncthreads();
    // linear coalesced write-out: feat[((b*NPIX)+pix)*24 + f]
    size_t base = ((size_t)b*NPIX + (size_t)(pix - t)) * 24;
    for (int q = t; q < 6144; q += 256)
        feat[base + q] = sf[q + q/24];
}

// ---------------- pass B: exclusive scan over 40000 counts ----------------
__global__ void scan_kernel(const int* __restrict__ counts,
                            int* __restrict__ bases,
                            int* __restrict__ cursor){
    __shared__ int part[1024];
    int t = threadIdx.x;
    const int TOT = BS*NCELL;       // 40000
    const int CH  = 40;
    int beg = t*CH;
    int s = 0;
    for (int i = 0; i < CH; ++i){
        int idx = beg + i;
        if (idx < TOT) s += counts[idx];
    }
    part[t] = s;
    __syncthreads();
    for (int off = 1; off < 1024; off <<= 1){
        int v = (t >= off) ? part[t-off] : 0;
        __syncthreads();
        part[t] += v;
        __syncthreads();
    }
    int run = (t == 0) ? 0 : part[t-1];
    for (int i = 0; i < CH; ++i){
        int idx = beg + i;
        if (idx < TOT){
            bases[idx]  = run;
            cursor[idx] = run;
            run += counts[idx];
        }
    }
}

// ---------------- pass C: scatter self-contained records ----------------
// record = {w0 = (wx*wy)*wz0, w1 = (wx*wy)*wz1, pix|z0<<17|z1<<24, 0}
__global__ __launch_bounds__(256)
void scatter_kernel(const float* __restrict__ obs,
                    const float* __restrict__ view_angles,
                    int* __restrict__ cursor,
                    uint4* __restrict__ records){
    int tid = blockIdx.x * 256 + threadIdx.x;
    int b   = tid / NPIX;
    int pix = tid % NPIX;
    Geo g = compute_geo(obs, view_angles, b, pix);
    #pragma unroll
    for (int cy = 0; cy < 2; ++cy)
    #pragma unroll
    for (int cx = 0; cx < 2; ++cx){
        float wxy = g.wx[cx] * g.wy[cy];
        if (g.sx[cx] && g.sy[cy] && (wxy != 0.f)){
            int cid = b*NCELL + g.yi[cy]*VR + g.xi[cx];
            int pos = atomicAdd(&cursor[cid], 1);
            float w0 = wxy * g.wz[0];        // matches ref (wx*wy)*wz order
            float w1 = wxy * g.wz[1];
            unsigned iw = (unsigned)pix | ((unsigned)g.zi[0] << 17)
                                        | ((unsigned)g.zi[1] << 24);
            records[pos] = make_uint4(__float_as_uint(w0), __float_as_uint(w1), iw, 0u);
        }
    }
}

// ---------------- pass D: per-cell LDS accumulation + z-projection ----------------
__global__ __launch_bounds__(256)
void accum_kernel(const uint4* __restrict__ records,
                  const float* __restrict__ feat,
                  const int* __restrict__ bases,
                  const int* __restrict__ cursor,
                  float* __restrict__ ahp,
                  float* __restrict__ allp,
                  float* __restrict__ out0){
    __shared__ float col[ZD*NF];        // 2000 floats
    __shared__ float pall[200], pag[200];

    int cid = blockIdx.x;
    int b   = cid / NCELL;
    int rest = cid % NCELL;
    int y = rest / VR;
    int x = rest % VR;
    int t = threadIdx.x;

    for (int i = t; i < ZD*NF; i += 256) col[i] = 0.f;
    __syncthreads();

    int start = bases[cid];
    int end   = cursor[cid];

    int r = t / NF;                     // record slot within chunk (0..9)
    int f = t % NF;
    bool act = t < 250;
    const float* feat_b = feat + (size_t)b*NPIX*24;

    for (int cb = start; cb < end; cb += 10){
        int idx = cb + r;
        if (act && idx < end){
            uint4 rec = records[idx];
            float w0 = __uint_as_float(rec.x);
            float w1 = __uint_as_float(rec.y);
            unsigned iw = rec.z;
            int pix = (int)(iw & 0x1FFFFu);
            int z0  = (int)((iw >> 17) & 0x7Fu);
            int z1  = (int)((iw >> 24) & 0x7Fu);
            float val = (f == 0) ? 1.f : feat_b[(size_t)pix*24 + (f-1)];
            if (w0 != 0.f) atomicAdd(&col[z0*NF + f], val * w0);
            if (w1 != 0.f) atomicAdd(&col[z1*NF + f], val * w1);
        }
    }
    __syncthreads();

    // projection: 200 threads = 25 f x 8 z-groups of 10
    if (t < 200){
        int ff = t % NF;
        int gq = t / NF;
        float sall = 0.f, sag = 0.f;
        for (int z = gq*10; z < gq*10 + 10; ++z){
            float rv = rintf(col[z*NF + ff]);
            sall += rv;
            if (z >= 11 && z < 49) sag += rv;   // agent-height z range
        }
        pall[t] = sall;
        pag[t]  = sag;
    }
    __syncthreads();
    if (t < NF){
        float a = 0.f, s = 0.f;
        #pragma unroll
        for (int gq = 0; gq < 8; ++gq){
            s += pall[gq*NF + t];
            a += pag[gq*NF + t];
        }
        ahp[(((size_t)b*NF + t)*VR + y)*VR + x] = a;
        if (t == 0){
            allp[((size_t)b*VR + y)*VR + x] = s;
            out0[(size_t)b*NCELL + y*VR + x] = clip01(a);   // fp_map_pred
        }
    }
}

// ---------------- fused rotate+translate grid_sample + max ----------------
__global__ __launch_bounds__(256)
void final_kernel(const float* __restrict__ ahp,
                  const float* __restrict__ allp,
                  const float* __restrict__ params,
                  const float* __restrict__ maps_last,
                  float* __restrict__ out1){
    int tid = blockIdx.x * blockDim.x + threadIdx.x;
    if (tid >= BS*MC*MC) return;
    int w = tid % MC;
    int h = (tid / MC) % MC;
    int b = tid / (MC*MC);

    float ct = params[b*4+0], st = params[b*4+1];
    float sx = params[b*4+2], sy = params[b*4+3];

    float gx = -1.f + 2.f*(float)w/479.f;
    float gy = -1.f + 2.f*(float)h/479.f;
    float ix = (gx + sx + 1.f)*0.5f*479.f;
    float iy = (gy + sy + 1.f)*0.5f*479.f;
    float x0 = floorf(ix), y0 = floorf(iy);
    float wx1 = ix - x0, wx0 = 1.f - wx1;
    float wy1 = iy - y0, wy0 = 1.f - wy1;

    int   offs[16];
    float wt16[16];
    int nz = 0;
    #pragma unroll
    for (int tc = 0; tc < 4; ++tc){
        float txf = (tc & 1) ? x0 + 1.f : x0;
        float tyf = (tc & 2) ? y0 + 1.f : y0;
        float wt  = ((tc & 1) ? wx1 : wx0) * ((tc & 2) ? wy1 : wy0);
        bool validT = (txf >= 0.f) && (txf <= 479.f) && (tyf >= 0.f) && (tyf <= 479.f);
        int txc = (int)fminf(fmaxf(txf, 0.f), 479.f);
        int tyc = (int)fminf(fmaxf(tyf, 0.f), 479.f);

        float gx2 = -1.f + 2.f*(float)txc/479.f;
        float gy2 = -1.f + 2.f*(float)tyc/479.f;
        float rgx = ct*gx2 - st*gy2;
        float rgy = st*gx2 + ct*gy2;
        float ixr = (rgx + 1.f)*0.5f*479.f;
        float iyr = (rgy + 1.f)*0.5f*479.f;
        float rx0 = floorf(ixr), ry0 = floorf(iyr);
        float rwx1 = ixr - rx0, rwx0 = 1.f - rwx1;
        float rwy1 = iyr - ry0, rwy0 = 1.f - rwy1;

        #pragma unroll
        for (int rc = 0; rc < 4; ++rc){
            int id = tc*4 + rc;
            float rxf = (rc & 1) ? rx0 + 1.f : rx0;
            float ryf = (rc & 2) ? ry0 + 1.f : ry0;
            float wr  = ((rc & 1) ? rwx1 : rwx0) * ((rc & 2) ? rwy1 : rwy0);
            bool validR = (rxf >= 0.f) && (rxf <= 479.f) && (ryf >= 0.f) && (ryf <= 479.f);
            int rxc = (int)fminf(fmaxf(rxf, 0.f), 479.f);
            int ryc = (int)fminf(fmaxf(ryf, 0.f), 479.f);
            bool inwin = validT && validR &&
                         (rxc >= 190) && (rxc < 290) && (ryc >= 240) && (ryc < 336);
            float wgt = wt * wr;
            if (inwin && wgt != 0.f){
                offs[id] = (ryc - 240)*VR + (rxc - 190);
                wt16[id] = wgt;
                nz++;
            } else {
                offs[id] = -1;
                wt16[id] = 0.f;
            }
        }
    }

    size_t outBase = (size_t)b*CC*MC*MC + (size_t)h*MC + w;
    if (nz == 0){
        #pragma unroll
        for (int ch = 0; ch < CC; ++ch){
            size_t o = outBase + (size_t)ch*MC*MC;
            out1[o] = fmaxf(maps_last[o], 0.f);
        }
        return;
    }

    const float* ahp_b  = ahp  + (size_t)b*NF*VR*VR;
    const float* allp_b = allp + (size_t)b*VR*VR;
    for (int ch = 0; ch < CC; ++ch){
        float acc = 0.f;
        if (ch != 2 && ch != 3){
            #pragma unroll
            for (int id = 0; id < 16; ++id){
                if (offs[id] >= 0){
                    float v;
                    if (ch == 0)      v = clip01(ahp_b[offs[id]]);
                    else if (ch == 1) v = clip01(allp_b[offs[id]]);
                    else              v = clip01(ahp_b[(size_t)(ch-3)*VR*VR + offs[id]] / 5.f);
                    acc += wt16[id] * v;
                }
            }
        }
        size_t o = outBase + (size_t)ch*MC*MC;
        out1[o] = fmaxf(maps_last[o], acc);
    }
}

extern "C" void kernel_launch(void* const* d_in, const int* in_sizes, int n_in,
                              void* d_out, int out_size, void* d_ws, size_t ws_size,
                              hipStream_t stream){
    const float* obs         = (const float*)d_in[0];
    const float* pose_obs    = (const float*)d_in[1];
    const float* maps_last   = (const float*)d_in[2];
    const float* poses_last  = (const float*)d_in[3];
    const float* view_angles = (const float*)d_in[4];
    float* out = (float*)d_out;

    const size_t OUT0 = (size_t)BS*VR*VR;        // 40000
    const size_t OUT1 = (size_t)BS*CC*MC*MC;     // 25,804,800
    float* out0 = out;
    float* out1 = out + OUT0;
    float* out2 = out + OUT0 + OUT1;
    float* out3 = out2 + BS*3;

    const size_t AHP_FLOATS  = (size_t)BS*NF*VR*VR;   // 1,000,000
    const size_t ALLP_FLOATS = (size_t)BS*VR*VR;      // 40,000
    const size_t NCID        = (size_t)BS*NCELL;      // 40,000
    const size_t FEAT_FLOATS = (size_t)BS*NPIX*24;    // 7,372,800 (29.5 MB)

    // small arrays read by final_kernel — always in ws
    float* ahp    = (float*)d_ws;
    float* allp   = ahp  + AHP_FLOATS;
    float* params = allp + ALLP_FLOATS;
    char*  ws_tail = (char*)(params + 16);
    size_t ws_used_small = (size_t)(ws_tail - (char*)d_ws);

    // big transient arrays: counts/bases/cursor + records + feat
    const size_t BIG_BYTES = NCID*3*4 + 32 + NREC_MAX*16 + FEAT_FLOATS*4;  // ~49.7 MB
    char* big;
    if (ws_size >= ws_used_small + BIG_BYTES){
        big = ws_tail;
    } else {
        // place in the tail of out1 (fully consumed before final_kernel writes out1)
        big = (char*)(out1 + OUT1) - BIG_BYTES;
        big = (char*)((uintptr_t)big & ~(uintptr_t)15);
    }
    int* counts = (int*)big;
    int* bases  = counts + NCID;
    int* cursor = bases  + NCID;
    uint4* records = (uint4*)(((uintptr_t)(cursor + NCID) + 15) & ~(uintptr_t)15);
    float* feat    = (float*)(records + NREC_MAX);

    hipMemsetAsync(counts, 0, NCID*4, stream);
    pose_kernel<<<1, 64, 0, stream>>>(pose_obs, poses_last, out2, out3, params);

    int nblk = (BS*NPIX)/256;   // 1200, exact
    prep_kernel<<<nblk, 256, 0, stream>>>(obs, view_angles, counts, feat);
    scan_kernel<<<1, 1024, 0, stream>>>(counts, bases, cursor);
    scatter_kernel<<<nblk, 256, 0, stream>>>(obs, view_angles, cursor, records);
    accum_kernel<<<(int)NCID, 256, 0, stream>>>(records, feat, bases, cursor,
                                                ahp, allp, out0);
    final_kernel<<<(BS*MC*MC + 255)/256, 256, 0, stream>>>(ahp, allp, params,
                                                           maps_last, out1);
}